// Round 12
// baseline (1304.646 us; speedup 1.0000x reference)
//
#include <hip/hip_runtime.h>
#include <hip/hip_bf16.h>

#define DIM 128
#define G4 512      // 4*DIM
#define NL 4
#define VOCAB 32000
#define BB 32
#define SS 256
#define ROWS (BB*SS)   // 8192

typedef __attribute__((ext_vector_type(8))) short short8;
typedef __attribute__((ext_vector_type(4))) float f32x4;
typedef __attribute__((ext_vector_type(4))) unsigned int uint4v;
typedef __attribute__((ext_vector_type(2))) _Float16 h2;

__device__ __forceinline__ float fexp_(float x){ return __builtin_amdgcn_exp2f(x * 1.44269504088896f); }
__device__ __forceinline__ float frcp_(float x){ return __builtin_amdgcn_rcpf(x); }
__device__ __forceinline__ float sigm_(float x){ return frcp_(1.f + fexp_(-x)); }
__device__ __forceinline__ float tanh_(float x){
    float ax = fabsf(x);
    float e = fexp_(-2.f * ax);
    float t = (1.f - e) * frcp_(1.f + e);
    return x < 0.f ? -t : t;
}
__device__ __forceinline__ h2 mkh(float a, float b){ h2 r; r.x = (_Float16)a; r.y = (_Float16)b; return r; }

#if __has_builtin(__builtin_amdgcn_fdot2)
#define FDOT2(w, d, acc) acc = __builtin_amdgcn_fdot2(w, d, acc, false);
#else
#define FDOT2(w, d, acc) acc = fmaf((float)(w).x, (float)(d).x, fmaf((float)(w).y, (float)(d).y, acc));
#endif
#define B2H(u) __builtin_bit_cast(h2, (unsigned)(u))

// ---- 32 named half2 regs (64 f16 weights = one K-half of one gate row) ----
#define WD32(p) h2 p##0,p##1,p##2,p##3,p##4,p##5,p##6,p##7,p##8,p##9,p##10,p##11, \
                   p##12,p##13,p##14,p##15,p##16,p##17,p##18,p##19,p##20,p##21,p##22,p##23, \
                   p##24,p##25,p##26,p##27,p##28,p##29,p##30,p##31;
#define WCVT32(p, src) { float4 t_; \
    t_=(src)[0];  p##0 =mkh(t_.x,t_.y); p##1 =mkh(t_.z,t_.w); \
    t_=(src)[1];  p##2 =mkh(t_.x,t_.y); p##3 =mkh(t_.z,t_.w); \
    t_=(src)[2];  p##4 =mkh(t_.x,t_.y); p##5 =mkh(t_.z,t_.w); \
    t_=(src)[3];  p##6 =mkh(t_.x,t_.y); p##7 =mkh(t_.z,t_.w); \
    t_=(src)[4];  p##8 =mkh(t_.x,t_.y); p##9 =mkh(t_.z,t_.w); \
    t_=(src)[5];  p##10=mkh(t_.x,t_.y); p##11=mkh(t_.z,t_.w); \
    t_=(src)[6];  p##12=mkh(t_.x,t_.y); p##13=mkh(t_.z,t_.w); \
    t_=(src)[7];  p##14=mkh(t_.x,t_.y); p##15=mkh(t_.z,t_.w); \
    t_=(src)[8];  p##16=mkh(t_.x,t_.y); p##17=mkh(t_.z,t_.w); \
    t_=(src)[9];  p##18=mkh(t_.x,t_.y); p##19=mkh(t_.z,t_.w); \
    t_=(src)[10]; p##20=mkh(t_.x,t_.y); p##21=mkh(t_.z,t_.w); \
    t_=(src)[11]; p##22=mkh(t_.x,t_.y); p##23=mkh(t_.z,t_.w); \
    t_=(src)[12]; p##24=mkh(t_.x,t_.y); p##25=mkh(t_.z,t_.w); \
    t_=(src)[13]; p##26=mkh(t_.x,t_.y); p##27=mkh(t_.z,t_.w); \
    t_=(src)[14]; p##28=mkh(t_.x,t_.y); p##29=mkh(t_.z,t_.w); \
    t_=(src)[15]; p##30=mkh(t_.x,t_.y); p##31=mkh(t_.z,t_.w); }
// dot of 32 weight-h2 against d0..d31
#define DT32(p, acc) \
    FDOT2(p##0,d0,acc)  FDOT2(p##1,d1,acc)  FDOT2(p##2,d2,acc)  FDOT2(p##3,d3,acc) \
    FDOT2(p##4,d4,acc)  FDOT2(p##5,d5,acc)  FDOT2(p##6,d6,acc)  FDOT2(p##7,d7,acc) \
    FDOT2(p##8,d8,acc)  FDOT2(p##9,d9,acc)  FDOT2(p##10,d10,acc) FDOT2(p##11,d11,acc) \
    FDOT2(p##12,d12,acc) FDOT2(p##13,d13,acc) FDOT2(p##14,d14,acc) FDOT2(p##15,d15,acc) \
    FDOT2(p##16,d16,acc) FDOT2(p##17,d17,acc) FDOT2(p##18,d18,acc) FDOT2(p##19,d19,acc) \
    FDOT2(p##20,d20,acc) FDOT2(p##21,d21,acc) FDOT2(p##22,d22,acc) FDOT2(p##23,d23,acc) \
    FDOT2(p##24,d24,acc) FDOT2(p##25,d25,acc) FDOT2(p##26,d26,acc) FDOT2(p##27,d27,acc) \
    FDOT2(p##28,d28,acc) FDOT2(p##29,d29,acc) FDOT2(p##30,d30,acc) FDOT2(p##31,d31,acc)
// dot of 32 weight-h2 against e0..e31 (second data bank — avoids WAR on d regs)
#define DT32E(p, acc) \
    FDOT2(p##0,e0,acc)  FDOT2(p##1,e1,acc)  FDOT2(p##2,e2,acc)  FDOT2(p##3,e3,acc) \
    FDOT2(p##4,e4,acc)  FDOT2(p##5,e5,acc)  FDOT2(p##6,e6,acc)  FDOT2(p##7,e7,acc) \
    FDOT2(p##8,e8,acc)  FDOT2(p##9,e9,acc)  FDOT2(p##10,e10,acc) FDOT2(p##11,e11,acc) \
    FDOT2(p##12,e12,acc) FDOT2(p##13,e13,acc) FDOT2(p##14,e14,acc) FDOT2(p##15,e15,acc) \
    FDOT2(p##16,e16,acc) FDOT2(p##17,e17,acc) FDOT2(p##18,e18,acc) FDOT2(p##19,e19,acc) \
    FDOT2(p##20,e20,acc) FDOT2(p##21,e21,acc) FDOT2(p##22,e22,acc) FDOT2(p##23,e23,acc) \
    FDOT2(p##24,e24,acc) FDOT2(p##25,e25,acc) FDOT2(p##26,e26,acc) FDOT2(p##27,e27,acc) \
    FDOT2(p##28,e28,acc) FDOT2(p##29,e29,acc) FDOT2(p##30,e30,acc) FDOT2(p##31,e31,acc)
// 64 f16 (128B) from LDS, uniform address -> broadcast, 8x ds_read_b128
#define RD32(base) { const uint4v* hc_ = (const uint4v*)(base); \
    uint4v q0_=hc_[0], q1_=hc_[1], q2_=hc_[2], q3_=hc_[3], \
           q4_=hc_[4], q5_=hc_[5], q6_=hc_[6], q7_=hc_[7]; \
    d0=B2H(q0_.x); d1=B2H(q0_.y); d2=B2H(q0_.z); d3=B2H(q0_.w); \
    d4=B2H(q1_.x); d5=B2H(q1_.y); d6=B2H(q1_.z); d7=B2H(q1_.w); \
    d8=B2H(q2_.x); d9=B2H(q2_.y); d10=B2H(q2_.z); d11=B2H(q2_.w); \
    d12=B2H(q3_.x); d13=B2H(q3_.y); d14=B2H(q3_.z); d15=B2H(q3_.w); \
    d16=B2H(q4_.x); d17=B2H(q4_.y); d18=B2H(q4_.z); d19=B2H(q4_.w); \
    d20=B2H(q5_.x); d21=B2H(q5_.y); d22=B2H(q5_.z); d23=B2H(q5_.w); \
    d24=B2H(q6_.x); d25=B2H(q6_.y); d26=B2H(q6_.z); d27=B2H(q6_.w); \
    d28=B2H(q7_.x); d29=B2H(q7_.y); d30=B2H(q7_.z); d31=B2H(q7_.w); }
#define RD32E(base) { const uint4v* hc_ = (const uint4v*)(base); \
    uint4v q0_=hc_[0], q1_=hc_[1], q2_=hc_[2], q3_=hc_[3], \
           q4_=hc_[4], q5_=hc_[5], q6_=hc_[6], q7_=hc_[7]; \
    e0=B2H(q0_.x); e1=B2H(q0_.y); e2=B2H(q0_.z); e3=B2H(q0_.w); \
    e4=B2H(q1_.x); e5=B2H(q1_.y); e6=B2H(q1_.z); e7=B2H(q1_.w); \
    e8=B2H(q2_.x); e9=B2H(q2_.y); e10=B2H(q2_.z); e11=B2H(q2_.w); \
    e12=B2H(q3_.x); e13=B2H(q3_.y); e14=B2H(q3_.z); e15=B2H(q3_.w); \
    e16=B2H(q4_.x); e17=B2H(q4_.y); e18=B2H(q4_.z); e19=B2H(q4_.w); \
    e20=B2H(q5_.x); e21=B2H(q5_.y); e22=B2H(q5_.z); e23=B2H(q5_.w); \
    e24=B2H(q6_.x); e25=B2H(q6_.y); e26=B2H(q6_.z); e27=B2H(q6_.w); \
    e28=B2H(q7_.x); e29=B2H(q7_.y); e30=B2H(q7_.z); e31=B2H(q7_.w); }

// full-K (128) fp32 macros for k_xw (1 gate/thread, broadcast h)
#define W_DECL_ALL \
    float4 w0,w1,w2,w3,w4,w5,w6,w7,w8,w9,w10,w11,w12,w13,w14,w15, \
           w16,w17,w18,w19,w20,w21,w22,w23,w24,w25,w26,w27,w28,w29,w30,w31;
#define W_LOAD(i) w##i = wr[i];
#define W_LOAD_ALL \
    W_LOAD(0) W_LOAD(1) W_LOAD(2) W_LOAD(3) W_LOAD(4) W_LOAD(5) W_LOAD(6) W_LOAD(7) \
    W_LOAD(8) W_LOAD(9) W_LOAD(10) W_LOAD(11) W_LOAD(12) W_LOAD(13) W_LOAD(14) W_LOAD(15) \
    W_LOAD(16) W_LOAD(17) W_LOAD(18) W_LOAD(19) W_LOAD(20) W_LOAD(21) W_LOAD(22) W_LOAD(23) \
    W_LOAD(24) W_LOAD(25) W_LOAD(26) W_LOAD(27) W_LOAD(28) W_LOAD(29) W_LOAD(30) W_LOAD(31)
#define FMA1(i, acc) acc = fmaf(h4[i].x, w##i.x, fmaf(h4[i].y, w##i.y, \
                      fmaf(h4[i].z, w##i.z, fmaf(h4[i].w, w##i.w, acc))));
#define DOT128(a0,a1,a2,a3) \
    FMA1(0,a0) FMA1(1,a0) FMA1(2,a0) FMA1(3,a0) FMA1(4,a0) FMA1(5,a0) FMA1(6,a0) FMA1(7,a0) \
    FMA1(8,a1) FMA1(9,a1) FMA1(10,a1) FMA1(11,a1) FMA1(12,a1) FMA1(13,a1) FMA1(14,a1) FMA1(15,a1) \
    FMA1(16,a2) FMA1(17,a2) FMA1(18,a2) FMA1(19,a2) FMA1(20,a2) FMA1(21,a2) FMA1(22,a2) FMA1(23,a2) \
    FMA1(24,a3) FMA1(25,a3) FMA1(26,a3) FMA1(27,a3) FMA1(28,a3) FMA1(29,a3) FMA1(30,a3) FMA1(31,a3)

// ---------------- K1: embedding gather ----------------
__global__ void k_embed(const int* __restrict__ x, const float* __restrict__ emb,
                        float* __restrict__ hseq){
    int i = blockIdx.x * blockDim.x + threadIdx.x;
    int row = i >> 5;
    int d4  = i & 31;
    int tok = x[row];
    ((float4*)hseq)[i] = ((const float4*)emb)[tok * 32 + d4];
}

// ---------------- K2: xw = hseq @ Wih^T + bih + bhh (cell-major layout) --------
__global__ __launch_bounds__(512, 2) void k_xw(const float* __restrict__ hseq,
                                               const float* Wih,
                                               const float* __restrict__ bih,
                                               const float* __restrict__ bhh,
                                               float* xw){
    __shared__ float hs[32 * DIM];
    int g = threadIdx.x;
    int r0 = blockIdx.x * 32;
    {
        const float4* src = (const float4*)(hseq + (size_t)r0 * DIM);
        float4* dst = (float4*)hs;
        for (int j = g; j < 32 * 32; j += 512) dst[j] = src[j];
    }
    int gg = ((g & 3) << 7) + (g >> 2);
    const float4* wr = (const float4*)(Wih + (size_t)gg * DIM);
    W_DECL_ALL
    W_LOAD_ALL
    float bias = bih[gg] + bhh[gg];
    __syncthreads();
    for (int r = 0; r < 32; ++r){
        const float4* h4 = (const float4*)(hs + r * DIM);
        float a0 = bias, a1 = 0.f, a2 = 0.f, a3 = 0.f;
        DOT128(a0, a1, a2, a3)
        xw[(size_t)(r0 + r) * G4 + g] = (a0 + a1) + (a2 + a3);
    }
}

// ---------------- K3: LSTM scan — fat threads + dual data banks ----------------
// Round-12 change: second data-register bank e0..e31 so BOTH h read-batches
// (16 ds_read_b128 total) issue together at step start; the second batch's LDS
// latency hides under the first 64-fdot2 pass (was WAR-serialized on d regs).
__global__ __launch_bounds__(256, 1) void k_scan(const float* __restrict__ xw,
                                                 const float* Whh,
                                                 float* hseq){
    __shared__ _Float16 hb[2][DIM];       // h ring (f16), uniform-read
    __shared__ float    stg[2][16][DIM];  // h staging for global flush
    const int tid = threadIdx.x;
    const int b = blockIdx.x;
    const int ci = tid >> 1;     // cell 0..127
    const int w  = tid & 1;      // gate-half: 0 -> {i,f}, 1 -> {g,o}

    WD32(pA) WD32(pB) WD32(pC) WD32(pD)   // gate 2w: A(K0-63)+B(K64-127); gate 2w+1: C+D
    {
        const float4* r0 = (const float4*)(Whh + (size_t)((2 * w    ) * DIM + ci) * DIM);
        const float4* r1 = (const float4*)(Whh + (size_t)((2 * w + 1) * DIM + ci) * DIM);
        WCVT32(pA, r0) WCVT32(pB, r0 + 16)
        WCVT32(pC, r1) WCVT32(pD, r1 + 16)
    }
    float cc = 0.f;
    if (tid < DIM) hb[0][tid] = (_Float16)0.f;
    const float2* xw2 = (const float2*)(xw + (size_t)b * SS * G4);   // [256][256] float2
    float* hout = hseq + (size_t)b * SS * DIM;
    __syncthreads();
    int p = 0;

#define SCAN_STEP(XC, CH, I) { \
        h2 d0,d1,d2,d3,d4,d5,d6,d7,d8,d9,d10,d11,d12,d13,d14,d15, \
           d16,d17,d18,d19,d20,d21,d22,d23,d24,d25,d26,d27,d28,d29,d30,d31; \
        h2 e0,e1,e2,e3,e4,e5,e6,e7,e8,e9,e10,e11,e12,e13,e14,e15, \
           e16,e17,e18,e19,e20,e21,e22,e23,e24,e25,e26,e27,e28,e29,e30,e31; \
        float s0 = XC.x, s1 = XC.y; \
        RD32(&hb[p][0]) \
        RD32E(&hb[p][64]) \
        DT32(pA, s0) DT32(pC, s1) \
        DT32E(pB, s0) DT32E(pD, s1) \
        float o0 = __shfl_xor(s0, 1), o1 = __shfl_xor(s1, 1); \
        float i_pre = w ? o0 : s0, f_pre = w ? o1 : s1; \
        float g_pre = w ? s0 : o0, o_pre = w ? s1 : o1; \
        float iv = sigm_(i_pre), fv = sigm_(f_pre); \
        float gv = tanh_(g_pre), ov = sigm_(o_pre); \
        cc = fv * cc + iv * gv; \
        float h = ov * tanh_(cc); \
        if (!w) hb[p ^ 1][ci] = (_Float16)h; \
        else    stg[(CH) & 1][I][ci] = h; \
        __syncthreads(); \
        p ^= 1; }

    for (int ch = 0; ch < 16; ++ch){
        if (ch > 0){   // flush previous chunk's 16x128 h tile (drains at next barrier)
#pragma unroll
            for (int j = 0; j < 2; ++j){
                int idx = j * 256 + tid;
                int r = idx >> 5, c4 = idx & 31;
                float4 v = *(const float4*)&stg[(ch - 1) & 1][r][c4 * 4];
                *(float4*)(hout + (size_t)((ch - 1) * 16 + r) * DIM + c4 * 4) = v;
            }
        }
        const int t0 = ch * 16;
        float2 xc0  = xw2[(t0 +  0) * 256 + tid], xc1  = xw2[(t0 +  1) * 256 + tid],
               xc2  = xw2[(t0 +  2) * 256 + tid], xc3  = xw2[(t0 +  3) * 256 + tid],
               xc4  = xw2[(t0 +  4) * 256 + tid], xc5  = xw2[(t0 +  5) * 256 + tid],
               xc6  = xw2[(t0 +  6) * 256 + tid], xc7  = xw2[(t0 +  7) * 256 + tid],
               xc8  = xw2[(t0 +  8) * 256 + tid], xc9  = xw2[(t0 +  9) * 256 + tid],
               xc10 = xw2[(t0 + 10) * 256 + tid], xc11 = xw2[(t0 + 11) * 256 + tid],
               xc12 = xw2[(t0 + 12) * 256 + tid], xc13 = xw2[(t0 + 13) * 256 + tid],
               xc14 = xw2[(t0 + 14) * 256 + tid], xc15 = xw2[(t0 + 15) * 256 + tid];
        SCAN_STEP(xc0,  ch, 0)  SCAN_STEP(xc1,  ch, 1)  SCAN_STEP(xc2,  ch, 2)  SCAN_STEP(xc3,  ch, 3)
        SCAN_STEP(xc4,  ch, 4)  SCAN_STEP(xc5,  ch, 5)  SCAN_STEP(xc6,  ch, 6)  SCAN_STEP(xc7,  ch, 7)
        SCAN_STEP(xc8,  ch, 8)  SCAN_STEP(xc9,  ch, 9)  SCAN_STEP(xc10, ch, 10) SCAN_STEP(xc11, ch, 11)
        SCAN_STEP(xc12, ch, 12) SCAN_STEP(xc13, ch, 13) SCAN_STEP(xc14, ch, 14) SCAN_STEP(xc15, ch, 15)
    }
    {   // final flush (chunk 15 -> stg buffer 1)
#pragma unroll
        for (int j = 0; j < 2; ++j){
            int idx = j * 256 + tid;
            int r = idx >> 5, c4 = idx & 31;
            float4 v = *(const float4*)&stg[1][r][c4 * 4];
            *(float4*)(hout + (size_t)(240 + r) * DIM + c4 * 4) = v;
        }
    }
#undef SCAN_STEP
}

// ---------------- K4: LayerNorm -> bf16 ----------------
__global__ void k_ln(const float* __restrict__ hseq, const float* __restrict__ gamma,
                     const float* __restrict__ beta, __hip_bfloat16* __restrict__ hn){
    int wid = threadIdx.x >> 6;
    int lane = threadIdx.x & 63;
    int row = blockIdx.x * 4 + wid;
    float2 hv = ((const float2*)(hseq + (size_t)row * DIM))[lane];
    float s = hv.x + hv.y;
    float sq = fmaf(hv.x, hv.x, hv.y * hv.y);
    for (int off = 32; off; off >>= 1){ s += __shfl_xor(s, off); sq += __shfl_xor(sq, off); }
    float mu = s * (1.f / 128.f);
    float var = sq * (1.f / 128.f) - mu * mu;
    float inv = rsqrtf(var + 1e-5f);
    float2 gv = ((const float2*)gamma)[lane];
    float2 bv = ((const float2*)beta)[lane];
    __hip_bfloat162 pr;
    pr.x = __float2bfloat16((hv.x - mu) * inv * gv.x + bv.x);
    pr.y = __float2bfloat16((hv.y - mu) * inv * gv.y + bv.y);
    ((__hip_bfloat162*)hn)[(size_t)row * 64 + lane] = pr;
}

// ---------------- K5: head_W fp32 -> bf16 ----------------
__global__ void k_cvt(const float* __restrict__ w, __hip_bfloat16* __restrict__ wb){
    int i = blockIdx.x * blockDim.x + threadIdx.x;
    float4 v = ((const float4*)w)[i];
    __hip_bfloat162 p0, p1;
    p0.x = __float2bfloat16(v.x); p0.y = __float2bfloat16(v.y);
    p1.x = __float2bfloat16(v.z); p1.y = __float2bfloat16(v.w);
    ((__hip_bfloat162*)wb)[2 * i]     = p0;
    ((__hip_bfloat162*)wb)[2 * i + 1] = p1;
}

// ---------------- K6: head GEMM — bm-major grid for B-panel reuse ----------------
// Round-12 change: grid (250,64)->(64,250), bm = blockIdx.x (x-major dispatch ->
// consecutive blocks share ONE B panel; B read ~once from HBM instead of 64x;
// A (2MB) stays L2-resident). 128x128 tile + NT stores kept (R10 A/B pinned).
__global__ __launch_bounds__(256) void k_head(const __hip_bfloat16* __restrict__ hn,
                                              const __hip_bfloat16* __restrict__ wb,
                                              const float* __restrict__ head_b,
                                              float* __restrict__ out){
    int bm = blockIdx.x;          // 64 row tiles of 128
    int bn = blockIdx.y;          // 250 col tiles of 128
    int wid = threadIdx.x >> 6;
    int lane = threadIdx.x & 63;
    int wr = wid >> 1, wc = wid & 1;
    int row0 = bm * 128 + wr * 64;
    int col0 = bn * 128 + wc * 64;
    const short* A  = (const short*)hn;   // [8192][128]
    const short* Bp = (const short*)wb;   // [32000][128]
    f32x4 zero = {0.f, 0.f, 0.f, 0.f};
    f32x4 acc[4][4];
#pragma unroll
    for (int i = 0; i < 4; ++i)
#pragma unroll
        for (int j = 0; j < 4; ++j) acc[i][j] = zero;
    int lrow = lane & 15;
    int kgr = (lane >> 4) * 8;
#pragma unroll
    for (int ks = 0; ks < 4; ++ks){
        short8 a[4], bf[4];
#pragma unroll
        for (int mi = 0; mi < 4; ++mi)
            a[mi] = *(const short8*)(A + (size_t)(row0 + mi * 16 + lrow) * DIM + ks * 32 + kgr);
#pragma unroll
        for (int ni = 0; ni < 4; ++ni)
            bf[ni] = *(const short8*)(Bp + (size_t)(col0 + ni * 16 + lrow) * DIM + ks * 32 + kgr);
#pragma unroll
        for (int mi = 0; mi < 4; ++mi)
#pragma unroll
            for (int ni = 0; ni < 4; ++ni)
                acc[mi][ni] = __builtin_amdgcn_mfma_f32_16x16x32_bf16(bf[ni], a[mi], acc[mi][ni], 0, 0, 0);
    }
    int csub = (lane >> 4) * 4;
#pragma unroll
    for (int ni = 0; ni < 4; ++ni){
        int cbase = col0 + ni * 16 + csub;
        float4 b4 = ((const float4*)head_b)[cbase >> 2];
#pragma unroll
        for (int mi = 0; mi < 4; ++mi){
            int row = row0 + mi * 16 + lrow;
            f32x4 v;
            v[0] = acc[mi][ni][0] + b4.x;
            v[1] = acc[mi][ni][1] + b4.y;
            v[2] = acc[mi][ni][2] + b4.z;
            v[3] = acc[mi][ni][3] + b4.w;
            __builtin_nontemporal_store(v, (f32x4*)(out + (size_t)row * VOCAB + cbase));
        }
    }
}

extern "C" void kernel_launch(void* const* d_in, const int* in_sizes, int n_in,
                              void* d_out, int out_size, void* d_ws, size_t ws_size,
                              hipStream_t stream){
    const int*   x     = (const int*)  d_in[0];
    const float* emb   = (const float*)d_in[1];
    const float* Wih   = (const float*)d_in[2];
    const float* Whh   = (const float*)d_in[3];
    const float* bih   = (const float*)d_in[4];
    const float* bhh   = (const float*)d_in[5];
    const float* gamma = (const float*)d_in[6];
    const float* beta  = (const float*)d_in[7];
    const float* headW = (const float*)d_in[8];
    const float* headb = (const float*)d_in[9];
    float* out = (float*)d_out;

    char* ws = (char*)d_ws;
    float* xw   = (float*)ws;                                  // 16 MB [8192][512] (cell-major)
    float* hseq = (float*)(ws + (16u << 20));                  // 4 MB  [8192][128]
    __hip_bfloat16* hn = (__hip_bfloat16*)(ws + (20u << 20));  // 2 MB
    __hip_bfloat16* wb = (__hip_bfloat16*)(ws + (22u << 20));  // 8 MB

    const size_t WSZ = (size_t)G4 * DIM;

    k_embed<<<1024, 256, 0, stream>>>(x, emb, hseq);
    k_cvt  <<<4000, 256, 0, stream>>>(headW, wb);
    for (int l = 0; l < NL; ++l){
        k_xw  <<<256, 512, 0, stream>>>(hseq, Wih + (size_t)l * WSZ,
                                        bih + l * G4, bhh + l * G4, xw);
        k_scan<<<32, 256, 0, stream>>>(xw, Whh + (size_t)l * WSZ, hseq);
    }
    k_ln   <<<2048, 256, 0, stream>>>(hseq, gamma, beta, hn);
    k_head <<<dim3(64, 250), 256, 0, stream>>>(hn, wb, headb, out);
}

// Round 13
// 1294.693 us; speedup vs baseline: 1.0077x; 1.0077x over previous
//
#include <hip/hip_runtime.h>
#include <hip/hip_bf16.h>

#define DIM 128
#define G4 512      // 4*DIM
#define NL 4
#define VOCAB 32000
#define BB 32
#define SS 256
#define ROWS (BB*SS)   // 8192

typedef __attribute__((ext_vector_type(8))) short short8;
typedef __attribute__((ext_vector_type(4))) float f32x4;
typedef __attribute__((ext_vector_type(4))) unsigned int uint4v;
typedef __attribute__((ext_vector_type(2))) _Float16 h2;

__device__ __forceinline__ float fexp_(float x){ return __builtin_amdgcn_exp2f(x * 1.44269504088896f); }
__device__ __forceinline__ float frcp_(float x){ return __builtin_amdgcn_rcpf(x); }
__device__ __forceinline__ float sigm_(float x){ return frcp_(1.f + fexp_(-x)); }
__device__ __forceinline__ float tanh_(float x){
    float ax = fabsf(x);
    float e = fexp_(-2.f * ax);
    float t = (1.f - e) * frcp_(1.f + e);
    return x < 0.f ? -t : t;
}
__device__ __forceinline__ h2 mkh(float a, float b){ h2 r; r.x = (_Float16)a; r.y = (_Float16)b; return r; }

#if __has_builtin(__builtin_amdgcn_fdot2)
#define FDOT2(w, d, acc) acc = __builtin_amdgcn_fdot2(w, d, acc, false);
#else
#define FDOT2(w, d, acc) acc = fmaf((float)(w).x, (float)(d).x, fmaf((float)(w).y, (float)(d).y, acc));
#endif
#define B2H(u) __builtin_bit_cast(h2, (unsigned)(u))

// ---- 32 named half2 regs (64 f16 weights = one K-half of one gate row) ----
#define WD32(p) h2 p##0,p##1,p##2,p##3,p##4,p##5,p##6,p##7,p##8,p##9,p##10,p##11, \
                   p##12,p##13,p##14,p##15,p##16,p##17,p##18,p##19,p##20,p##21,p##22,p##23, \
                   p##24,p##25,p##26,p##27,p##28,p##29,p##30,p##31;
#define WCVT32(p, src) { float4 t_; \
    t_=(src)[0];  p##0 =mkh(t_.x,t_.y); p##1 =mkh(t_.z,t_.w); \
    t_=(src)[1];  p##2 =mkh(t_.x,t_.y); p##3 =mkh(t_.z,t_.w); \
    t_=(src)[2];  p##4 =mkh(t_.x,t_.y); p##5 =mkh(t_.z,t_.w); \
    t_=(src)[3];  p##6 =mkh(t_.x,t_.y); p##7 =mkh(t_.z,t_.w); \
    t_=(src)[4];  p##8 =mkh(t_.x,t_.y); p##9 =mkh(t_.z,t_.w); \
    t_=(src)[5];  p##10=mkh(t_.x,t_.y); p##11=mkh(t_.z,t_.w); \
    t_=(src)[6];  p##12=mkh(t_.x,t_.y); p##13=mkh(t_.z,t_.w); \
    t_=(src)[7];  p##14=mkh(t_.x,t_.y); p##15=mkh(t_.z,t_.w); \
    t_=(src)[8];  p##16=mkh(t_.x,t_.y); p##17=mkh(t_.z,t_.w); \
    t_=(src)[9];  p##18=mkh(t_.x,t_.y); p##19=mkh(t_.z,t_.w); \
    t_=(src)[10]; p##20=mkh(t_.x,t_.y); p##21=mkh(t_.z,t_.w); \
    t_=(src)[11]; p##22=mkh(t_.x,t_.y); p##23=mkh(t_.z,t_.w); \
    t_=(src)[12]; p##24=mkh(t_.x,t_.y); p##25=mkh(t_.z,t_.w); \
    t_=(src)[13]; p##26=mkh(t_.x,t_.y); p##27=mkh(t_.z,t_.w); \
    t_=(src)[14]; p##28=mkh(t_.x,t_.y); p##29=mkh(t_.z,t_.w); \
    t_=(src)[15]; p##30=mkh(t_.x,t_.y); p##31=mkh(t_.z,t_.w); }
// dot of 32 weight-h2 against d0..d31, SPLIT into two 16-deep chains (accA, accB)
// -> halves the dependent-accumulate chain (round-13 change)
#define DT32_2(p, accA, accB) \
    FDOT2(p##0,d0,accA)  FDOT2(p##1,d1,accA)  FDOT2(p##2,d2,accA)  FDOT2(p##3,d3,accA) \
    FDOT2(p##4,d4,accA)  FDOT2(p##5,d5,accA)  FDOT2(p##6,d6,accA)  FDOT2(p##7,d7,accA) \
    FDOT2(p##8,d8,accA)  FDOT2(p##9,d9,accA)  FDOT2(p##10,d10,accA) FDOT2(p##11,d11,accA) \
    FDOT2(p##12,d12,accA) FDOT2(p##13,d13,accA) FDOT2(p##14,d14,accA) FDOT2(p##15,d15,accA) \
    FDOT2(p##16,d16,accB) FDOT2(p##17,d17,accB) FDOT2(p##18,d18,accB) FDOT2(p##19,d19,accB) \
    FDOT2(p##20,d20,accB) FDOT2(p##21,d21,accB) FDOT2(p##22,d22,accB) FDOT2(p##23,d23,accB) \
    FDOT2(p##24,d24,accB) FDOT2(p##25,d25,accB) FDOT2(p##26,d26,accB) FDOT2(p##27,d27,accB) \
    FDOT2(p##28,d28,accB) FDOT2(p##29,d29,accB) FDOT2(p##30,d30,accB) FDOT2(p##31,d31,accB)
// 64 f16 (128B) from LDS, uniform address -> broadcast, 8x ds_read_b128
#define RD32(base) { const uint4v* hc_ = (const uint4v*)(base); \
    uint4v q0_=hc_[0], q1_=hc_[1], q2_=hc_[2], q3_=hc_[3], \
           q4_=hc_[4], q5_=hc_[5], q6_=hc_[6], q7_=hc_[7]; \
    d0=B2H(q0_.x); d1=B2H(q0_.y); d2=B2H(q0_.z); d3=B2H(q0_.w); \
    d4=B2H(q1_.x); d5=B2H(q1_.y); d6=B2H(q1_.z); d7=B2H(q1_.w); \
    d8=B2H(q2_.x); d9=B2H(q2_.y); d10=B2H(q2_.z); d11=B2H(q2_.w); \
    d12=B2H(q3_.x); d13=B2H(q3_.y); d14=B2H(q3_.z); d15=B2H(q3_.w); \
    d16=B2H(q4_.x); d17=B2H(q4_.y); d18=B2H(q4_.z); d19=B2H(q4_.w); \
    d20=B2H(q5_.x); d21=B2H(q5_.y); d22=B2H(q5_.z); d23=B2H(q5_.w); \
    d24=B2H(q6_.x); d25=B2H(q6_.y); d26=B2H(q6_.z); d27=B2H(q6_.w); \
    d28=B2H(q7_.x); d29=B2H(q7_.y); d30=B2H(q7_.z); d31=B2H(q7_.w); }

// full-K (128) fp32 macros for k_xw (1 gate/thread, broadcast h)
#define W_DECL_ALL \
    float4 w0,w1,w2,w3,w4,w5,w6,w7,w8,w9,w10,w11,w12,w13,w14,w15, \
           w16,w17,w18,w19,w20,w21,w22,w23,w24,w25,w26,w27,w28,w29,w30,w31;
#define W_LOAD(i) w##i = wr[i];
#define W_LOAD_ALL \
    W_LOAD(0) W_LOAD(1) W_LOAD(2) W_LOAD(3) W_LOAD(4) W_LOAD(5) W_LOAD(6) W_LOAD(7) \
    W_LOAD(8) W_LOAD(9) W_LOAD(10) W_LOAD(11) W_LOAD(12) W_LOAD(13) W_LOAD(14) W_LOAD(15) \
    W_LOAD(16) W_LOAD(17) W_LOAD(18) W_LOAD(19) W_LOAD(20) W_LOAD(21) W_LOAD(22) W_LOAD(23) \
    W_LOAD(24) W_LOAD(25) W_LOAD(26) W_LOAD(27) W_LOAD(28) W_LOAD(29) W_LOAD(30) W_LOAD(31)
#define FMA1(i, acc) acc = fmaf(h4[i].x, w##i.x, fmaf(h4[i].y, w##i.y, \
                      fmaf(h4[i].z, w##i.z, fmaf(h4[i].w, w##i.w, acc))));
#define DOT128(a0,a1,a2,a3) \
    FMA1(0,a0) FMA1(1,a0) FMA1(2,a0) FMA1(3,a0) FMA1(4,a0) FMA1(5,a0) FMA1(6,a0) FMA1(7,a0) \
    FMA1(8,a1) FMA1(9,a1) FMA1(10,a1) FMA1(11,a1) FMA1(12,a1) FMA1(13,a1) FMA1(14,a1) FMA1(15,a1) \
    FMA1(16,a2) FMA1(17,a2) FMA1(18,a2) FMA1(19,a2) FMA1(20,a2) FMA1(21,a2) FMA1(22,a2) FMA1(23,a2) \
    FMA1(24,a3) FMA1(25,a3) FMA1(26,a3) FMA1(27,a3) FMA1(28,a3) FMA1(29,a3) FMA1(30,a3) FMA1(31,a3)

// ---------------- K1: embedding gather ----------------
__global__ void k_embed(const int* __restrict__ x, const float* __restrict__ emb,
                        float* __restrict__ hseq){
    int i = blockIdx.x * blockDim.x + threadIdx.x;
    int row = i >> 5;
    int d4  = i & 31;
    int tok = x[row];
    ((float4*)hseq)[i] = ((const float4*)emb)[tok * 32 + d4];
}

// ---------------- K2: xw = hseq @ Wih^T + bih + bhh (cell-major layout) --------
__global__ __launch_bounds__(512, 2) void k_xw(const float* __restrict__ hseq,
                                               const float* Wih,
                                               const float* __restrict__ bih,
                                               const float* __restrict__ bhh,
                                               float* xw){
    __shared__ float hs[32 * DIM];
    int g = threadIdx.x;
    int r0 = blockIdx.x * 32;
    {
        const float4* src = (const float4*)(hseq + (size_t)r0 * DIM);
        float4* dst = (float4*)hs;
        for (int j = g; j < 32 * 32; j += 512) dst[j] = src[j];
    }
    int gg = ((g & 3) << 7) + (g >> 2);
    const float4* wr = (const float4*)(Wih + (size_t)gg * DIM);
    W_DECL_ALL
    W_LOAD_ALL
    float bias = bih[gg] + bhh[gg];
    __syncthreads();
    for (int r = 0; r < 32; ++r){
        const float4* h4 = (const float4*)(hs + r * DIM);
        float a0 = bias, a1 = 0.f, a2 = 0.f, a3 = 0.f;
        DOT128(a0, a1, a2, a3)
        xw[(size_t)(r0 + r) * G4 + g] = (a0 + a1) + (a2 + a3);
    }
}

// ---------------- K3: LSTM scan — fat threads, 4-chain accumulation ----------
// R11 base (best-known: 256 thr, thread owns 2 full-K gate rows, pair-exchange,
// single d-bank). Round-13 change: each gate's 64-fdot2 accumulation splits
// into FOUR 16-deep chains (8 accs/thread) + tree combine — dependent-chain
// ~500 cyc -> ~130 cyc, step becomes issue-bound.
__global__ __launch_bounds__(256, 1) void k_scan(const float* __restrict__ xw,
                                                 const float* Whh,
                                                 float* hseq){
    __shared__ _Float16 hb[2][DIM];       // h ring (f16), uniform-read
    __shared__ float    stg[2][16][DIM];  // h staging for global flush
    const int tid = threadIdx.x;
    const int b = blockIdx.x;
    const int ci = tid >> 1;     // cell 0..127
    const int w  = tid & 1;      // gate-half: 0 -> {i,f}, 1 -> {g,o}

    WD32(pA) WD32(pB) WD32(pC) WD32(pD)   // gate 2w: A(K0-63)+B(K64-127); gate 2w+1: C+D
    {
        const float4* r0 = (const float4*)(Whh + (size_t)((2 * w    ) * DIM + ci) * DIM);
        const float4* r1 = (const float4*)(Whh + (size_t)((2 * w + 1) * DIM + ci) * DIM);
        WCVT32(pA, r0) WCVT32(pB, r0 + 16)
        WCVT32(pC, r1) WCVT32(pD, r1 + 16)
    }
    float cc = 0.f;
    if (tid < DIM) hb[0][tid] = (_Float16)0.f;
    const float2* xw2 = (const float2*)(xw + (size_t)b * SS * G4);   // [256][256] float2
    float* hout = hseq + (size_t)b * SS * DIM;
    __syncthreads();
    int p = 0;

#define SCAN_STEP(XC, CH, I) { \
        h2 d0,d1,d2,d3,d4,d5,d6,d7,d8,d9,d10,d11,d12,d13,d14,d15, \
           d16,d17,d18,d19,d20,d21,d22,d23,d24,d25,d26,d27,d28,d29,d30,d31; \
        float s0a = XC.x, s0b = 0.f, s0c = 0.f, s0d = 0.f; \
        float s1a = XC.y, s1b = 0.f, s1c = 0.f, s1d = 0.f; \
        RD32(&hb[p][0]) \
        DT32_2(pA, s0a, s0b) \
        DT32_2(pC, s1a, s1b) \
        RD32(&hb[p][64]) \
        DT32_2(pB, s0c, s0d) \
        DT32_2(pD, s1c, s1d) \
        float s0 = (s0a + s0b) + (s0c + s0d); \
        float s1 = (s1a + s1b) + (s1c + s1d); \
        float o0 = __shfl_xor(s0, 1), o1 = __shfl_xor(s1, 1); \
        float i_pre = w ? o0 : s0, f_pre = w ? o1 : s1; \
        float g_pre = w ? s0 : o0, o_pre = w ? s1 : o1; \
        float iv = sigm_(i_pre), fv = sigm_(f_pre); \
        float gv = tanh_(g_pre), ov = sigm_(o_pre); \
        cc = fv * cc + iv * gv; \
        float h = ov * tanh_(cc); \
        if (!w) hb[p ^ 1][ci] = (_Float16)h; \
        else    stg[(CH) & 1][I][ci] = h; \
        __syncthreads(); \
        p ^= 1; }

    for (int ch = 0; ch < 16; ++ch){
        if (ch > 0){   // flush previous chunk's 16x128 h tile (drains at next barrier)
#pragma unroll
            for (int j = 0; j < 2; ++j){
                int idx = j * 256 + tid;
                int r = idx >> 5, c4 = idx & 31;
                float4 v = *(const float4*)&stg[(ch - 1) & 1][r][c4 * 4];
                *(float4*)(hout + (size_t)((ch - 1) * 16 + r) * DIM + c4 * 4) = v;
            }
        }
        const int t0 = ch * 16;
        float2 xc0  = xw2[(t0 +  0) * 256 + tid], xc1  = xw2[(t0 +  1) * 256 + tid],
               xc2  = xw2[(t0 +  2) * 256 + tid], xc3  = xw2[(t0 +  3) * 256 + tid],
               xc4  = xw2[(t0 +  4) * 256 + tid], xc5  = xw2[(t0 +  5) * 256 + tid],
               xc6  = xw2[(t0 +  6) * 256 + tid], xc7  = xw2[(t0 +  7) * 256 + tid],
               xc8  = xw2[(t0 +  8) * 256 + tid], xc9  = xw2[(t0 +  9) * 256 + tid],
               xc10 = xw2[(t0 + 10) * 256 + tid], xc11 = xw2[(t0 + 11) * 256 + tid],
               xc12 = xw2[(t0 + 12) * 256 + tid], xc13 = xw2[(t0 + 13) * 256 + tid],
               xc14 = xw2[(t0 + 14) * 256 + tid], xc15 = xw2[(t0 + 15) * 256 + tid];
        SCAN_STEP(xc0,  ch, 0)  SCAN_STEP(xc1,  ch, 1)  SCAN_STEP(xc2,  ch, 2)  SCAN_STEP(xc3,  ch, 3)
        SCAN_STEP(xc4,  ch, 4)  SCAN_STEP(xc5,  ch, 5)  SCAN_STEP(xc6,  ch, 6)  SCAN_STEP(xc7,  ch, 7)
        SCAN_STEP(xc8,  ch, 8)  SCAN_STEP(xc9,  ch, 9)  SCAN_STEP(xc10, ch, 10) SCAN_STEP(xc11, ch, 11)
        SCAN_STEP(xc12, ch, 12) SCAN_STEP(xc13, ch, 13) SCAN_STEP(xc14, ch, 14) SCAN_STEP(xc15, ch, 15)
    }
    {   // final flush (chunk 15 -> stg buffer 1)
#pragma unroll
        for (int j = 0; j < 2; ++j){
            int idx = j * 256 + tid;
            int r = idx >> 5, c4 = idx & 31;
            float4 v = *(const float4*)&stg[1][r][c4 * 4];
            *(float4*)(hout + (size_t)(240 + r) * DIM + c4 * 4) = v;
        }
    }
#undef SCAN_STEP
}

// ---------------- K4: LayerNorm -> bf16 ----------------
__global__ void k_ln(const float* __restrict__ hseq, const float* __restrict__ gamma,
                     const float* __restrict__ beta, __hip_bfloat16* __restrict__ hn){
    int wid = threadIdx.x >> 6;
    int lane = threadIdx.x & 63;
    int row = blockIdx.x * 4 + wid;
    float2 hv = ((const float2*)(hseq + (size_t)row * DIM))[lane];
    float s = hv.x + hv.y;
    float sq = fmaf(hv.x, hv.x, hv.y * hv.y);
    for (int off = 32; off; off >>= 1){ s += __shfl_xor(s, off); sq += __shfl_xor(sq, off); }
    float mu = s * (1.f / 128.f);
    float var = sq * (1.f / 128.f) - mu * mu;
    float inv = rsqrtf(var + 1e-5f);
    float2 gv = ((const float2*)gamma)[lane];
    float2 bv = ((const float2*)beta)[lane];
    __hip_bfloat162 pr;
    pr.x = __float2bfloat16((hv.x - mu) * inv * gv.x + bv.x);
    pr.y = __float2bfloat16((hv.y - mu) * inv * gv.y + bv.y);
    ((__hip_bfloat162*)hn)[(size_t)row * 64 + lane] = pr;
}

// ---------------- K5: head_W fp32 -> bf16 ----------------
__global__ void k_cvt(const float* __restrict__ w, __hip_bfloat16* __restrict__ wb){
    int i = blockIdx.x * blockDim.x + threadIdx.x;
    float4 v = ((const float4*)w)[i];
    __hip_bfloat162 p0, p1;
    p0.x = __float2bfloat16(v.x); p0.y = __float2bfloat16(v.y);
    p1.x = __float2bfloat16(v.z); p1.y = __float2bfloat16(v.w);
    ((__hip_bfloat162*)wb)[2 * i]     = p0;
    ((__hip_bfloat162*)wb)[2 * i + 1] = p1;
}

// ---------------- K6: head GEMM — R11 grid/NT + paired-line store order --------
// Round-13 change: epilogue loops swapped to mi-outer / ni-inner. The 4 NT
// stores for one 16-row set now issue back-to-back and cover 256B contiguous
// per row (2 full 128B lines) -> NT write-combining can merge half-lines
// (ni-outer order interleaved different rows between the two halves of each
// line -> suspected 2x HBM write inflation).
__global__ __launch_bounds__(256) void k_head(const __hip_bfloat16* __restrict__ hn,
                                              const __hip_bfloat16* __restrict__ wb,
                                              const float* __restrict__ head_b,
                                              float* __restrict__ out){
    int bn = blockIdx.x;          // 250 col tiles (x-major dispatch, R11-pinned)
    int bm = blockIdx.y;          // 64 row tiles
    int wid = threadIdx.x >> 6;
    int lane = threadIdx.x & 63;
    int wr = wid >> 1, wc = wid & 1;
    int row0 = bm * 128 + wr * 64;
    int col0 = bn * 128 + wc * 64;
    const short* A  = (const short*)hn;   // [8192][128]
    const short* Bp = (const short*)wb;   // [32000][128]
    f32x4 zero = {0.f, 0.f, 0.f, 0.f};
    f32x4 acc[4][4];
#pragma unroll
    for (int i = 0; i < 4; ++i)
#pragma unroll
        for (int j = 0; j < 4; ++j) acc[i][j] = zero;
    int lrow = lane & 15;
    int kgr = (lane >> 4) * 8;
#pragma unroll
    for (int ks = 0; ks < 4; ++ks){
        short8 a[4], bf[4];
#pragma unroll
        for (int mi = 0; mi < 4; ++mi)
            a[mi] = *(const short8*)(A + (size_t)(row0 + mi * 16 + lrow) * DIM + ks * 32 + kgr);
#pragma unroll
        for (int ni = 0; ni < 4; ++ni)
            bf[ni] = *(const short8*)(Bp + (size_t)(col0 + ni * 16 + lrow) * DIM + ks * 32 + kgr);
#pragma unroll
        for (int mi = 0; mi < 4; ++mi)
#pragma unroll
            for (int ni = 0; ni < 4; ++ni)
                acc[mi][ni] = __builtin_amdgcn_mfma_f32_16x16x32_bf16(bf[ni], a[mi], acc[mi][ni], 0, 0, 0);
    }
    int csub = (lane >> 4) * 4;
    float4 b4[4];
#pragma unroll
    for (int ni = 0; ni < 4; ++ni)
        b4[ni] = ((const float4*)head_b)[(col0 + ni * 16 + csub) >> 2];
#pragma unroll
    for (int mi = 0; mi < 4; ++mi){
        int row = row0 + mi * 16 + lrow;
        size_t rbase = (size_t)row * VOCAB;
#pragma unroll
        for (int ni = 0; ni < 4; ++ni){
            int cbase = col0 + ni * 16 + csub;
            f32x4 v;
            v[0] = acc[mi][ni][0] + b4[ni].x;
            v[1] = acc[mi][ni][1] + b4[ni].y;
            v[2] = acc[mi][ni][2] + b4[ni].z;
            v[3] = acc[mi][ni][3] + b4[ni].w;
            __builtin_nontemporal_store(v, (f32x4*)(out + rbase + cbase));
        }
    }
}

extern "C" void kernel_launch(void* const* d_in, const int* in_sizes, int n_in,
                              void* d_out, int out_size, void* d_ws, size_t ws_size,
                              hipStream_t stream){
    const int*   x     = (const int*)  d_in[0];
    const float* emb   = (const float*)d_in[1];
    const float* Wih   = (const float*)d_in[2];
    const float* Whh   = (const float*)d_in[3];
    const float* bih   = (const float*)d_in[4];
    const float* bhh   = (const float*)d_in[5];
    const float* gamma = (const float*)d_in[6];
    const float* beta  = (const float*)d_in[7];
    const float* headW = (const float*)d_in[8];
    const float* headb = (const float*)d_in[9];
    float* out = (float*)d_out;

    char* ws = (char*)d_ws;
    float* xw   = (float*)ws;                                  // 16 MB [8192][512] (cell-major)
    float* hseq = (float*)(ws + (16u << 20));                  // 4 MB  [8192][128]
    __hip_bfloat16* hn = (__hip_bfloat16*)(ws + (20u << 20));  // 2 MB
    __hip_bfloat16* wb = (__hip_bfloat16*)(ws + (22u << 20));  // 8 MB

    const size_t WSZ = (size_t)G4 * DIM;

    k_embed<<<1024, 256, 0, stream>>>(x, emb, hseq);
    k_cvt  <<<4000, 256, 0, stream>>>(headW, wb);
    for (int l = 0; l < NL; ++l){
        k_xw  <<<256, 512, 0, stream>>>(hseq, Wih + (size_t)l * WSZ,
                                        bih + l * G4, bhh + l * G4, xw);
        k_scan<<<32, 256, 0, stream>>>(xw, Whh + (size_t)l * WSZ, hseq);
    }
    k_ln   <<<2048, 256, 0, stream>>>(hseq, gamma, beta, hn);
    k_head <<<dim3(250, 64), 256, 0, stream>>>(hn, wb, headb, out);
}

// Round 14
// 1258.031 us; speedup vs baseline: 1.0371x; 1.0291x over previous
//
#include <hip/hip_runtime.h>
#include <hip/hip_bf16.h>

#define DIM 128
#define G4 512      // 4*DIM
#define NL 4
#define VOCAB 32000
#define BB 32
#define SS 256
#define ROWS (BB*SS)   // 8192

typedef __attribute__((ext_vector_type(8))) short short8;
typedef __attribute__((ext_vector_type(4))) float f32x4;
typedef __attribute__((ext_vector_type(4))) unsigned int uint4v;
typedef __attribute__((ext_vector_type(2))) _Float16 h2;

__device__ __forceinline__ float fexp_(float x){ return __builtin_amdgcn_exp2f(x * 1.44269504088896f); }
__device__ __forceinline__ float frcp_(float x){ return __builtin_amdgcn_rcpf(x); }
__device__ __forceinline__ float sigm_(float x){ return frcp_(1.f + fexp_(-x)); }
__device__ __forceinline__ float tanh_(float x){
    float ax = fabsf(x);
    float e = fexp_(-2.f * ax);
    float t = (1.f - e) * frcp_(1.f + e);
    return x < 0.f ? -t : t;
}
__device__ __forceinline__ h2 mkh(float a, float b){ h2 r; r.x = (_Float16)a; r.y = (_Float16)b; return r; }

#if __has_builtin(__builtin_amdgcn_fdot2)
#define FDOT2(w, d, acc) acc = __builtin_amdgcn_fdot2(w, d, acc, false);
#else
#define FDOT2(w, d, acc) acc = fmaf((float)(w).x, (float)(d).x, fmaf((float)(w).y, (float)(d).y, acc));
#endif
#define B2H(u) __builtin_bit_cast(h2, (unsigned)(u))

// ---- 32 named half2 regs (64 f16 weights = one K-half of one gate row) ----
#define WD32(p) h2 p##0,p##1,p##2,p##3,p##4,p##5,p##6,p##7,p##8,p##9,p##10,p##11, \
                   p##12,p##13,p##14,p##15,p##16,p##17,p##18,p##19,p##20,p##21,p##22,p##23, \
                   p##24,p##25,p##26,p##27,p##28,p##29,p##30,p##31;
#define WCVT32(p, src) { float4 t_; \
    t_=(src)[0];  p##0 =mkh(t_.x,t_.y); p##1 =mkh(t_.z,t_.w); \
    t_=(src)[1];  p##2 =mkh(t_.x,t_.y); p##3 =mkh(t_.z,t_.w); \
    t_=(src)[2];  p##4 =mkh(t_.x,t_.y); p##5 =mkh(t_.z,t_.w); \
    t_=(src)[3];  p##6 =mkh(t_.x,t_.y); p##7 =mkh(t_.z,t_.w); \
    t_=(src)[4];  p##8 =mkh(t_.x,t_.y); p##9 =mkh(t_.z,t_.w); \
    t_=(src)[5];  p##10=mkh(t_.x,t_.y); p##11=mkh(t_.z,t_.w); \
    t_=(src)[6];  p##12=mkh(t_.x,t_.y); p##13=mkh(t_.z,t_.w); \
    t_=(src)[7];  p##14=mkh(t_.x,t_.y); p##15=mkh(t_.z,t_.w); \
    t_=(src)[8];  p##16=mkh(t_.x,t_.y); p##17=mkh(t_.z,t_.w); \
    t_=(src)[9];  p##18=mkh(t_.x,t_.y); p##19=mkh(t_.z,t_.w); \
    t_=(src)[10]; p##20=mkh(t_.x,t_.y); p##21=mkh(t_.z,t_.w); \
    t_=(src)[11]; p##22=mkh(t_.x,t_.y); p##23=mkh(t_.z,t_.w); \
    t_=(src)[12]; p##24=mkh(t_.x,t_.y); p##25=mkh(t_.z,t_.w); \
    t_=(src)[13]; p##26=mkh(t_.x,t_.y); p##27=mkh(t_.z,t_.w); \
    t_=(src)[14]; p##28=mkh(t_.x,t_.y); p##29=mkh(t_.z,t_.w); \
    t_=(src)[15]; p##30=mkh(t_.x,t_.y); p##31=mkh(t_.z,t_.w); }
// dot of 32 weight-h2 against d0..d31 (R11-exact single-bank form)
#define DT32(p, acc) \
    FDOT2(p##0,d0,acc)  FDOT2(p##1,d1,acc)  FDOT2(p##2,d2,acc)  FDOT2(p##3,d3,acc) \
    FDOT2(p##4,d4,acc)  FDOT2(p##5,d5,acc)  FDOT2(p##6,d6,acc)  FDOT2(p##7,d7,acc) \
    FDOT2(p##8,d8,acc)  FDOT2(p##9,d9,acc)  FDOT2(p##10,d10,acc) FDOT2(p##11,d11,acc) \
    FDOT2(p##12,d12,acc) FDOT2(p##13,d13,acc) FDOT2(p##14,d14,acc) FDOT2(p##15,d15,acc) \
    FDOT2(p##16,d16,acc) FDOT2(p##17,d17,acc) FDOT2(p##18,d18,acc) FDOT2(p##19,d19,acc) \
    FDOT2(p##20,d20,acc) FDOT2(p##21,d21,acc) FDOT2(p##22,d22,acc) FDOT2(p##23,d23,acc) \
    FDOT2(p##24,d24,acc) FDOT2(p##25,d25,acc) FDOT2(p##26,d26,acc) FDOT2(p##27,d27,acc) \
    FDOT2(p##28,d28,acc) FDOT2(p##29,d29,acc) FDOT2(p##30,d30,acc) FDOT2(p##31,d31,acc)
// 64 f16 (128B) from LDS, uniform address -> broadcast, 8x ds_read_b128
#define RD32(base) { const uint4v* hc_ = (const uint4v*)(base); \
    uint4v q0_=hc_[0], q1_=hc_[1], q2_=hc_[2], q3_=hc_[3], \
           q4_=hc_[4], q5_=hc_[5], q6_=hc_[6], q7_=hc_[7]; \
    d0=B2H(q0_.x); d1=B2H(q0_.y); d2=B2H(q0_.z); d3=B2H(q0_.w); \
    d4=B2H(q1_.x); d5=B2H(q1_.y); d6=B2H(q1_.z); d7=B2H(q1_.w); \
    d8=B2H(q2_.x); d9=B2H(q2_.y); d10=B2H(q2_.z); d11=B2H(q2_.w); \
    d12=B2H(q3_.x); d13=B2H(q3_.y); d14=B2H(q3_.z); d15=B2H(q3_.w); \
    d16=B2H(q4_.x); d17=B2H(q4_.y); d18=B2H(q4_.z); d19=B2H(q4_.w); \
    d20=B2H(q5_.x); d21=B2H(q5_.y); d22=B2H(q5_.z); d23=B2H(q5_.w); \
    d24=B2H(q6_.x); d25=B2H(q6_.y); d26=B2H(q6_.z); d27=B2H(q6_.w); \
    d28=B2H(q7_.x); d29=B2H(q7_.y); d30=B2H(q7_.z); d31=B2H(q7_.w); }

// full-K (128) fp32 macros for k_xw (1 gate/thread, broadcast h)
#define W_DECL_ALL \
    float4 w0,w1,w2,w3,w4,w5,w6,w7,w8,w9,w10,w11,w12,w13,w14,w15, \
           w16,w17,w18,w19,w20,w21,w22,w23,w24,w25,w26,w27,w28,w29,w30,w31;
#define W_LOAD(i) w##i = wr[i];
#define W_LOAD_ALL \
    W_LOAD(0) W_LOAD(1) W_LOAD(2) W_LOAD(3) W_LOAD(4) W_LOAD(5) W_LOAD(6) W_LOAD(7) \
    W_LOAD(8) W_LOAD(9) W_LOAD(10) W_LOAD(11) W_LOAD(12) W_LOAD(13) W_LOAD(14) W_LOAD(15) \
    W_LOAD(16) W_LOAD(17) W_LOAD(18) W_LOAD(19) W_LOAD(20) W_LOAD(21) W_LOAD(22) W_LOAD(23) \
    W_LOAD(24) W_LOAD(25) W_LOAD(26) W_LOAD(27) W_LOAD(28) W_LOAD(29) W_LOAD(30) W_LOAD(31)
#define FMA1(i, acc) acc = fmaf(h4[i].x, w##i.x, fmaf(h4[i].y, w##i.y, \
                      fmaf(h4[i].z, w##i.z, fmaf(h4[i].w, w##i.w, acc))));
#define DOT128(a0,a1,a2,a3) \
    FMA1(0,a0) FMA1(1,a0) FMA1(2,a0) FMA1(3,a0) FMA1(4,a0) FMA1(5,a0) FMA1(6,a0) FMA1(7,a0) \
    FMA1(8,a1) FMA1(9,a1) FMA1(10,a1) FMA1(11,a1) FMA1(12,a1) FMA1(13,a1) FMA1(14,a1) FMA1(15,a1) \
    FMA1(16,a2) FMA1(17,a2) FMA1(18,a2) FMA1(19,a2) FMA1(20,a2) FMA1(21,a2) FMA1(22,a2) FMA1(23,a2) \
    FMA1(24,a3) FMA1(25,a3) FMA1(26,a3) FMA1(27,a3) FMA1(28,a3) FMA1(29,a3) FMA1(30,a3) FMA1(31,a3)

// ---------------- K1: embedding gather ----------------
__global__ void k_embed(const int* __restrict__ x, const float* __restrict__ emb,
                        float* __restrict__ hseq){
    int i = blockIdx.x * blockDim.x + threadIdx.x;
    int row = i >> 5;
    int d4  = i & 31;
    int tok = x[row];
    ((float4*)hseq)[i] = ((const float4*)emb)[tok * 32 + d4];
}

// ---------------- K2: xw = hseq @ Wih^T + bih + bhh (cell-major layout) --------
__global__ __launch_bounds__(512, 2) void k_xw(const float* __restrict__ hseq,
                                               const float* Wih,
                                               const float* __restrict__ bih,
                                               const float* __restrict__ bhh,
                                               float* xw){
    __shared__ float hs[32 * DIM];
    int g = threadIdx.x;
    int r0 = blockIdx.x * 32;
    {
        const float4* src = (const float4*)(hseq + (size_t)r0 * DIM);
        float4* dst = (float4*)hs;
        for (int j = g; j < 32 * 32; j += 512) dst[j] = src[j];
    }
    int gg = ((g & 3) << 7) + (g >> 2);
    const float4* wr = (const float4*)(Wih + (size_t)gg * DIM);
    W_DECL_ALL
    W_LOAD_ALL
    float bias = bih[gg] + bhh[gg];
    __syncthreads();
    for (int r = 0; r < 32; ++r){
        const float4* h4 = (const float4*)(hs + r * DIM);
        float a0 = bias, a1 = 0.f, a2 = 0.f, a3 = 0.f;
        DOT128(a0, a1, a2, a3)
        xw[(size_t)(r0 + r) * G4 + g] = (a0 + a1) + (a2 + a3);
    }
}

// ---------------- K3: LSTM scan — R11 fat-thread base, 32-step chunks ----------
// R11-exact step (single d-bank, two 64-deep chains, pair-exchange, 1 barrier).
// Round-14 change: chunk depth 16 -> 32 (32 named float2 xw regs): the
// once-per-chunk vmcnt(0) drain (~600-900 cyc vs L2/L3) halves per-step,
// ~40-55 -> ~20-27 cyc/step. +32 VGPRs (budget 512 at launch_bounds(256,1)).
__global__ __launch_bounds__(256, 1) void k_scan(const float* __restrict__ xw,
                                                 const float* Whh,
                                                 float* hseq){
    __shared__ _Float16 hb[2][DIM];       // h ring (f16), uniform-read
    __shared__ float    stg[2][32][DIM];  // h staging, 32-step chunks (32 KB)
    const int tid = threadIdx.x;
    const int b = blockIdx.x;
    const int ci = tid >> 1;     // cell 0..127
    const int w  = tid & 1;      // gate-half: 0 -> {i,f}, 1 -> {g,o}

    WD32(pA) WD32(pB) WD32(pC) WD32(pD)   // gate 2w: A(K0-63)+B(K64-127); gate 2w+1: C+D
    {
        const float4* r0 = (const float4*)(Whh + (size_t)((2 * w    ) * DIM + ci) * DIM);
        const float4* r1 = (const float4*)(Whh + (size_t)((2 * w + 1) * DIM + ci) * DIM);
        WCVT32(pA, r0) WCVT32(pB, r0 + 16)
        WCVT32(pC, r1) WCVT32(pD, r1 + 16)
    }
    float cc = 0.f;
    if (tid < DIM) hb[0][tid] = (_Float16)0.f;
    const float2* xw2 = (const float2*)(xw + (size_t)b * SS * G4);   // [256][256] float2
    float* hout = hseq + (size_t)b * SS * DIM;
    __syncthreads();
    int p = 0;

#define SCAN_STEP(XC, CH, I) { \
        h2 d0,d1,d2,d3,d4,d5,d6,d7,d8,d9,d10,d11,d12,d13,d14,d15, \
           d16,d17,d18,d19,d20,d21,d22,d23,d24,d25,d26,d27,d28,d29,d30,d31; \
        float s0 = XC.x, s1 = XC.y; \
        RD32(&hb[p][0]) \
        DT32(pA, s0) DT32(pC, s1) \
        RD32(&hb[p][64]) \
        DT32(pB, s0) DT32(pD, s1) \
        float o0 = __shfl_xor(s0, 1), o1 = __shfl_xor(s1, 1); \
        float i_pre = w ? o0 : s0, f_pre = w ? o1 : s1; \
        float g_pre = w ? s0 : o0, o_pre = w ? s1 : o1; \
        float iv = sigm_(i_pre), fv = sigm_(f_pre); \
        float gv = tanh_(g_pre), ov = sigm_(o_pre); \
        cc = fv * cc + iv * gv; \
        float h = ov * tanh_(cc); \
        if (!w) hb[p ^ 1][ci] = (_Float16)h; \
        else    stg[(CH) & 1][I][ci] = h; \
        __syncthreads(); \
        p ^= 1; }

    for (int ch = 0; ch < 8; ++ch){
        if (ch > 0){   // flush previous chunk's 32x128 h tile (drains at next barrier)
#pragma unroll
            for (int j = 0; j < 4; ++j){
                int idx = j * 256 + tid;
                int r = idx >> 5, c4 = idx & 31;
                float4 v = *(const float4*)&stg[(ch - 1) & 1][r][c4 * 4];
                *(float4*)(hout + (size_t)((ch - 1) * 32 + r) * DIM + c4 * 4) = v;
            }
        }
        const int t0 = ch * 32;
        float2 xc0  = xw2[(t0 +  0) * 256 + tid], xc1  = xw2[(t0 +  1) * 256 + tid],
               xc2  = xw2[(t0 +  2) * 256 + tid], xc3  = xw2[(t0 +  3) * 256 + tid],
               xc4  = xw2[(t0 +  4) * 256 + tid], xc5  = xw2[(t0 +  5) * 256 + tid],
               xc6  = xw2[(t0 +  6) * 256 + tid], xc7  = xw2[(t0 +  7) * 256 + tid],
               xc8  = xw2[(t0 +  8) * 256 + tid], xc9  = xw2[(t0 +  9) * 256 + tid],
               xc10 = xw2[(t0 + 10) * 256 + tid], xc11 = xw2[(t0 + 11) * 256 + tid],
               xc12 = xw2[(t0 + 12) * 256 + tid], xc13 = xw2[(t0 + 13) * 256 + tid],
               xc14 = xw2[(t0 + 14) * 256 + tid], xc15 = xw2[(t0 + 15) * 256 + tid],
               xc16 = xw2[(t0 + 16) * 256 + tid], xc17 = xw2[(t0 + 17) * 256 + tid],
               xc18 = xw2[(t0 + 18) * 256 + tid], xc19 = xw2[(t0 + 19) * 256 + tid],
               xc20 = xw2[(t0 + 20) * 256 + tid], xc21 = xw2[(t0 + 21) * 256 + tid],
               xc22 = xw2[(t0 + 22) * 256 + tid], xc23 = xw2[(t0 + 23) * 256 + tid],
               xc24 = xw2[(t0 + 24) * 256 + tid], xc25 = xw2[(t0 + 25) * 256 + tid],
               xc26 = xw2[(t0 + 26) * 256 + tid], xc27 = xw2[(t0 + 27) * 256 + tid],
               xc28 = xw2[(t0 + 28) * 256 + tid], xc29 = xw2[(t0 + 29) * 256 + tid],
               xc30 = xw2[(t0 + 30) * 256 + tid], xc31 = xw2[(t0 + 31) * 256 + tid];
        SCAN_STEP(xc0,  ch, 0)  SCAN_STEP(xc1,  ch, 1)  SCAN_STEP(xc2,  ch, 2)  SCAN_STEP(xc3,  ch, 3)
        SCAN_STEP(xc4,  ch, 4)  SCAN_STEP(xc5,  ch, 5)  SCAN_STEP(xc6,  ch, 6)  SCAN_STEP(xc7,  ch, 7)
        SCAN_STEP(xc8,  ch, 8)  SCAN_STEP(xc9,  ch, 9)  SCAN_STEP(xc10, ch, 10) SCAN_STEP(xc11, ch, 11)
        SCAN_STEP(xc12, ch, 12) SCAN_STEP(xc13, ch, 13) SCAN_STEP(xc14, ch, 14) SCAN_STEP(xc15, ch, 15)
        SCAN_STEP(xc16, ch, 16) SCAN_STEP(xc17, ch, 17) SCAN_STEP(xc18, ch, 18) SCAN_STEP(xc19, ch, 19)
        SCAN_STEP(xc20, ch, 20) SCAN_STEP(xc21, ch, 21) SCAN_STEP(xc22, ch, 22) SCAN_STEP(xc23, ch, 23)
        SCAN_STEP(xc24, ch, 24) SCAN_STEP(xc25, ch, 25) SCAN_STEP(xc26, ch, 26) SCAN_STEP(xc27, ch, 27)
        SCAN_STEP(xc28, ch, 28) SCAN_STEP(xc29, ch, 29) SCAN_STEP(xc30, ch, 30) SCAN_STEP(xc31, ch, 31)
    }
    {   // final flush (chunk 7 -> stg buffer 1)
#pragma unroll
        for (int j = 0; j < 4; ++j){
            int idx = j * 256 + tid;
            int r = idx >> 5, c4 = idx & 31;
            float4 v = *(const float4*)&stg[1][r][c4 * 4];
            *(float4*)(hout + (size_t)(224 + r) * DIM + c4 * 4) = v;
        }
    }
#undef SCAN_STEP
}

// ---------------- K4: LayerNorm -> bf16 ----------------
__global__ void k_ln(const float* __restrict__ hseq, const float* __restrict__ gamma,
                     const float* __restrict__ beta, __hip_bfloat16* __restrict__ hn){
    int wid = threadIdx.x >> 6;
    int lane = threadIdx.x & 63;
    int row = blockIdx.x * 4 + wid;
    float2 hv = ((const float2*)(hseq + (size_t)row * DIM))[lane];
    float s = hv.x + hv.y;
    float sq = fmaf(hv.x, hv.x, hv.y * hv.y);
    for (int off = 32; off; off >>= 1){ s += __shfl_xor(s, off); sq += __shfl_xor(sq, off); }
    float mu = s * (1.f / 128.f);
    float var = sq * (1.f / 128.f) - mu * mu;
    float inv = rsqrtf(var + 1e-5f);
    float2 gv = ((const float2*)gamma)[lane];
    float2 bv = ((const float2*)beta)[lane];
    __hip_bfloat162 pr;
    pr.x = __float2bfloat16((hv.x - mu) * inv * gv.x + bv.x);
    pr.y = __float2bfloat16((hv.y - mu) * inv * gv.y + bv.y);
    ((__hip_bfloat162*)hn)[(size_t)row * 64 + lane] = pr;
}

// ---------------- K5: head_W fp32 -> bf16 ----------------
__global__ void k_cvt(const float* __restrict__ w, __hip_bfloat16* __restrict__ wb){
    int i = blockIdx.x * blockDim.x + threadIdx.x;
    float4 v = ((const float4*)w)[i];
    __hip_bfloat162 p0, p1;
    p0.x = __float2bfloat16(v.x); p0.y = __float2bfloat16(v.y);
    p1.x = __float2bfloat16(v.z); p1.y = __float2bfloat16(v.w);
    ((__hip_bfloat162*)wb)[2 * i]     = p0;
    ((__hip_bfloat162*)wb)[2 * i + 1] = p1;
}

// ---------------- K6: head GEMM — R11-exact (128x128, NT stores, ni-outer) -----
__global__ __launch_bounds__(256) void k_head(const __hip_bfloat16* __restrict__ hn,
                                              const __hip_bfloat16* __restrict__ wb,
                                              const float* __restrict__ head_b,
                                              float* __restrict__ out){
    int bn = blockIdx.x;
    int bm = blockIdx.y;
    int wid = threadIdx.x >> 6;
    int lane = threadIdx.x & 63;
    int wr = wid >> 1, wc = wid & 1;
    int row0 = bm * 128 + wr * 64;
    int col0 = bn * 128 + wc * 64;
    const short* A  = (const short*)hn;   // [8192][128]
    const short* Bp = (const short*)wb;   // [32000][128]
    f32x4 zero = {0.f, 0.f, 0.f, 0.f};
    f32x4 acc[4][4];
#pragma unroll
    for (int i = 0; i < 4; ++i)
#pragma unroll
        for (int j = 0; j < 4; ++j) acc[i][j] = zero;
    int lrow = lane & 15;
    int kgr = (lane >> 4) * 8;
#pragma unroll
    for (int ks = 0; ks < 4; ++ks){
        short8 a[4], bf[4];
#pragma unroll
        for (int mi = 0; mi < 4; ++mi)
            a[mi] = *(const short8*)(A + (size_t)(row0 + mi * 16 + lrow) * DIM + ks * 32 + kgr);
#pragma unroll
        for (int ni = 0; ni < 4; ++ni)
            bf[ni] = *(const short8*)(Bp + (size_t)(col0 + ni * 16 + lrow) * DIM + ks * 32 + kgr);
#pragma unroll
        for (int mi = 0; mi < 4; ++mi)
#pragma unroll
            for (int ni = 0; ni < 4; ++ni)
                acc[mi][ni] = __builtin_amdgcn_mfma_f32_16x16x32_bf16(bf[ni], a[mi], acc[mi][ni], 0, 0, 0);
    }
    int csub = (lane >> 4) * 4;
#pragma unroll
    for (int ni = 0; ni < 4; ++ni){
        int cbase = col0 + ni * 16 + csub;
        float4 b4 = ((const float4*)head_b)[cbase >> 2];
#pragma unroll
        for (int mi = 0; mi < 4; ++mi){
            int row = row0 + mi * 16 + lrow;
            f32x4 v;
            v[0] = acc[mi][ni][0] + b4.x;
            v[1] = acc[mi][ni][1] + b4.y;
            v[2] = acc[mi][ni][2] + b4.z;
            v[3] = acc[mi][ni][3] + b4.w;
            __builtin_nontemporal_store(v, (f32x4*)(out + (size_t)row * VOCAB + cbase));
        }
    }
}

extern "C" void kernel_launch(void* const* d_in, const int* in_sizes, int n_in,
                              void* d_out, int out_size, void* d_ws, size_t ws_size,
                              hipStream_t stream){
    const int*   x     = (const int*)  d_in[0];
    const float* emb   = (const float*)d_in[1];
    const float* Wih   = (const float*)d_in[2];
    const float* Whh   = (const float*)d_in[3];
    const float* bih   = (const float*)d_in[4];
    const float* bhh   = (const float*)d_in[5];
    const float* gamma = (const float*)d_in[6];
    const float* beta  = (const float*)d_in[7];
    const float* headW = (const float*)d_in[8];
    const float* headb = (const float*)d_in[9];
    float* out = (float*)d_out;

    char* ws = (char*)d_ws;
    float* xw   = (float*)ws;                                  // 16 MB [8192][512] (cell-major)
    float* hseq = (float*)(ws + (16u << 20));                  // 4 MB  [8192][128]
    __hip_bfloat16* hn = (__hip_bfloat16*)(ws + (20u << 20));  // 2 MB
    __hip_bfloat16* wb = (__hip_bfloat16*)(ws + (22u << 20));  // 8 MB

    const size_t WSZ = (size_t)G4 * DIM;

    k_embed<<<1024, 256, 0, stream>>>(x, emb, hseq);
    k_cvt  <<<4000, 256, 0, stream>>>(headW, wb);
    for (int l = 0; l < NL; ++l){
        k_xw  <<<256, 512, 0, stream>>>(hseq, Wih + (size_t)l * WSZ,
                                        bih + l * G4, bhh + l * G4, xw);
        k_scan<<<32, 256, 0, stream>>>(xw, Whh + (size_t)l * WSZ, hseq);
    }
    k_ln   <<<2048, 256, 0, stream>>>(hseq, gamma, beta, hn);
    k_head <<<dim3(250, 64), 256, 0, stream>>>(hn, wb, headb, out);
}

// Round 15
// 1247.753 us; speedup vs baseline: 1.0456x; 1.0082x over previous
//
#include <hip/hip_runtime.h>
#include <hip/hip_bf16.h>

#define DIM 128
#define G4 512      // 4*DIM
#define NL 4
#define VOCAB 32000
#define BB 32
#define SS 256
#define ROWS (BB*SS)   // 8192

typedef __attribute__((ext_vector_type(8))) short short8;
typedef __attribute__((ext_vector_type(4))) float f32x4;
typedef __attribute__((ext_vector_type(4))) unsigned int uint4v;
typedef __attribute__((ext_vector_type(2))) _Float16 h2;

__device__ __forceinline__ float fexp_(float x){ return __builtin_amdgcn_exp2f(x * 1.44269504088896f); }
__device__ __forceinline__ float frcp_(float x){ return __builtin_amdgcn_rcpf(x); }
__device__ __forceinline__ float sigm_(float x){ return frcp_(1.f + fexp_(-x)); }
__device__ __forceinline__ float tanh_(float x){
    float ax = fabsf(x);
    float e = fexp_(-2.f * ax);
    float t = (1.f - e) * frcp_(1.f + e);
    return x < 0.f ? -t : t;
}
__device__ __forceinline__ h2 mkh(float a, float b){ h2 r; r.x = (_Float16)a; r.y = (_Float16)b; return r; }

#if __has_builtin(__builtin_amdgcn_fdot2)
#define FDOT2(w, d, acc) acc = __builtin_amdgcn_fdot2(w, d, acc, false);
#else
#define FDOT2(w, d, acc) acc = fmaf((float)(w).x, (float)(d).x, fmaf((float)(w).y, (float)(d).y, acc));
#endif
#define B2H(u) __builtin_bit_cast(h2, (unsigned)(u))

// ---- 32 named half2 regs (64 f16 weights = one K-half of one gate row) ----
#define WD32(p) h2 p##0,p##1,p##2,p##3,p##4,p##5,p##6,p##7,p##8,p##9,p##10,p##11, \
                   p##12,p##13,p##14,p##15,p##16,p##17,p##18,p##19,p##20,p##21,p##22,p##23, \
                   p##24,p##25,p##26,p##27,p##28,p##29,p##30,p##31;
#define WCVT32(p, src) { float4 t_; \
    t_=(src)[0];  p##0 =mkh(t_.x,t_.y); p##1 =mkh(t_.z,t_.w); \
    t_=(src)[1];  p##2 =mkh(t_.x,t_.y); p##3 =mkh(t_.z,t_.w); \
    t_=(src)[2];  p##4 =mkh(t_.x,t_.y); p##5 =mkh(t_.z,t_.w); \
    t_=(src)[3];  p##6 =mkh(t_.x,t_.y); p##7 =mkh(t_.z,t_.w); \
    t_=(src)[4];  p##8 =mkh(t_.x,t_.y); p##9 =mkh(t_.z,t_.w); \
    t_=(src)[5];  p##10=mkh(t_.x,t_.y); p##11=mkh(t_.z,t_.w); \
    t_=(src)[6];  p##12=mkh(t_.x,t_.y); p##13=mkh(t_.z,t_.w); \
    t_=(src)[7];  p##14=mkh(t_.x,t_.y); p##15=mkh(t_.z,t_.w); \
    t_=(src)[8];  p##16=mkh(t_.x,t_.y); p##17=mkh(t_.z,t_.w); \
    t_=(src)[9];  p##18=mkh(t_.x,t_.y); p##19=mkh(t_.z,t_.w); \
    t_=(src)[10]; p##20=mkh(t_.x,t_.y); p##21=mkh(t_.z,t_.w); \
    t_=(src)[11]; p##22=mkh(t_.x,t_.y); p##23=mkh(t_.z,t_.w); \
    t_=(src)[12]; p##24=mkh(t_.x,t_.y); p##25=mkh(t_.z,t_.w); \
    t_=(src)[13]; p##26=mkh(t_.x,t_.y); p##27=mkh(t_.z,t_.w); \
    t_=(src)[14]; p##28=mkh(t_.x,t_.y); p##29=mkh(t_.z,t_.w); \
    t_=(src)[15]; p##30=mkh(t_.x,t_.y); p##31=mkh(t_.z,t_.w); }
// dot of 32 weight-h2 against d0..d31 (R11-exact single-bank form)
#define DT32(p, acc) \
    FDOT2(p##0,d0,acc)  FDOT2(p##1,d1,acc)  FDOT2(p##2,d2,acc)  FDOT2(p##3,d3,acc) \
    FDOT2(p##4,d4,acc)  FDOT2(p##5,d5,acc)  FDOT2(p##6,d6,acc)  FDOT2(p##7,d7,acc) \
    FDOT2(p##8,d8,acc)  FDOT2(p##9,d9,acc)  FDOT2(p##10,d10,acc) FDOT2(p##11,d11,acc) \
    FDOT2(p##12,d12,acc) FDOT2(p##13,d13,acc) FDOT2(p##14,d14,acc) FDOT2(p##15,d15,acc) \
    FDOT2(p##16,d16,acc) FDOT2(p##17,d17,acc) FDOT2(p##18,d18,acc) FDOT2(p##19,d19,acc) \
    FDOT2(p##20,d20,acc) FDOT2(p##21,d21,acc) FDOT2(p##22,d22,acc) FDOT2(p##23,d23,acc) \
    FDOT2(p##24,d24,acc) FDOT2(p##25,d25,acc) FDOT2(p##26,d26,acc) FDOT2(p##27,d27,acc) \
    FDOT2(p##28,d28,acc) FDOT2(p##29,d29,acc) FDOT2(p##30,d30,acc) FDOT2(p##31,d31,acc)
// 64 f16 (128B) from LDS, uniform address -> broadcast, 8x ds_read_b128
#define RD32(base) { const uint4v* hc_ = (const uint4v*)(base); \
    uint4v q0_=hc_[0], q1_=hc_[1], q2_=hc_[2], q3_=hc_[3], \
           q4_=hc_[4], q5_=hc_[5], q6_=hc_[6], q7_=hc_[7]; \
    d0=B2H(q0_.x); d1=B2H(q0_.y); d2=B2H(q0_.z); d3=B2H(q0_.w); \
    d4=B2H(q1_.x); d5=B2H(q1_.y); d6=B2H(q1_.z); d7=B2H(q1_.w); \
    d8=B2H(q2_.x); d9=B2H(q2_.y); d10=B2H(q2_.z); d11=B2H(q2_.w); \
    d12=B2H(q3_.x); d13=B2H(q3_.y); d14=B2H(q3_.z); d15=B2H(q3_.w); \
    d16=B2H(q4_.x); d17=B2H(q4_.y); d18=B2H(q4_.z); d19=B2H(q4_.w); \
    d20=B2H(q5_.x); d21=B2H(q5_.y); d22=B2H(q5_.z); d23=B2H(q5_.w); \
    d24=B2H(q6_.x); d25=B2H(q6_.y); d26=B2H(q6_.z); d27=B2H(q6_.w); \
    d28=B2H(q7_.x); d29=B2H(q7_.y); d30=B2H(q7_.z); d31=B2H(q7_.w); }

// full-K (128) fp32 macros for k_xw (1 gate/thread, broadcast h)
#define W_DECL_ALL \
    float4 w0,w1,w2,w3,w4,w5,w6,w7,w8,w9,w10,w11,w12,w13,w14,w15, \
           w16,w17,w18,w19,w20,w21,w22,w23,w24,w25,w26,w27,w28,w29,w30,w31;
#define W_LOAD(i) w##i = wr[i];
#define W_LOAD_ALL \
    W_LOAD(0) W_LOAD(1) W_LOAD(2) W_LOAD(3) W_LOAD(4) W_LOAD(5) W_LOAD(6) W_LOAD(7) \
    W_LOAD(8) W_LOAD(9) W_LOAD(10) W_LOAD(11) W_LOAD(12) W_LOAD(13) W_LOAD(14) W_LOAD(15) \
    W_LOAD(16) W_LOAD(17) W_LOAD(18) W_LOAD(19) W_LOAD(20) W_LOAD(21) W_LOAD(22) W_LOAD(23) \
    W_LOAD(24) W_LOAD(25) W_LOAD(26) W_LOAD(27) W_LOAD(28) W_LOAD(29) W_LOAD(30) W_LOAD(31)
#define FMA1(i, acc) acc = fmaf(h4[i].x, w##i.x, fmaf(h4[i].y, w##i.y, \
                      fmaf(h4[i].z, w##i.z, fmaf(h4[i].w, w##i.w, acc))));
#define DOT128(a0,a1,a2,a3) \
    FMA1(0,a0) FMA1(1,a0) FMA1(2,a0) FMA1(3,a0) FMA1(4,a0) FMA1(5,a0) FMA1(6,a0) FMA1(7,a0) \
    FMA1(8,a1) FMA1(9,a1) FMA1(10,a1) FMA1(11,a1) FMA1(12,a1) FMA1(13,a1) FMA1(14,a1) FMA1(15,a1) \
    FMA1(16,a2) FMA1(17,a2) FMA1(18,a2) FMA1(19,a2) FMA1(20,a2) FMA1(21,a2) FMA1(22,a2) FMA1(23,a2) \
    FMA1(24,a3) FMA1(25,a3) FMA1(26,a3) FMA1(27,a3) FMA1(28,a3) FMA1(29,a3) FMA1(30,a3) FMA1(31,a3)

// ---------------- K1: embedding gather ----------------
__global__ void k_embed(const int* __restrict__ x, const float* __restrict__ emb,
                        float* __restrict__ hseq){
    int i = blockIdx.x * blockDim.x + threadIdx.x;
    int row = i >> 5;
    int d4  = i & 31;
    int tok = x[row];
    ((float4*)hseq)[i] = ((const float4*)emb)[tok * 32 + d4];
}

// ---------------- K2: xw = hseq @ Wih^T + bih + bhh (cell-major layout) --------
__global__ __launch_bounds__(512, 2) void k_xw(const float* __restrict__ hseq,
                                               const float* Wih,
                                               const float* __restrict__ bih,
                                               const float* __restrict__ bhh,
                                               float* xw){
    __shared__ float hs[32 * DIM];
    int g = threadIdx.x;
    int r0 = blockIdx.x * 32;
    {
        const float4* src = (const float4*)(hseq + (size_t)r0 * DIM);
        float4* dst = (float4*)hs;
        for (int j = g; j < 32 * 32; j += 512) dst[j] = src[j];
    }
    int gg = ((g & 3) << 7) + (g >> 2);
    const float4* wr = (const float4*)(Wih + (size_t)gg * DIM);
    W_DECL_ALL
    W_LOAD_ALL
    float bias = bih[gg] + bhh[gg];
    __syncthreads();
    for (int r = 0; r < 32; ++r){
        const float4* h4 = (const float4*)(hs + r * DIM);
        float a0 = bias, a1 = 0.f, a2 = 0.f, a3 = 0.f;
        DOT128(a0, a1, a2, a3)
        xw[(size_t)(r0 + r) * G4 + g] = (a0 + a1) + (a2 + a3);
    }
}

// ---------------- K3: LSTM scan — R11-exact fat-thread version ----------------
// (best-known: 256 thr, thread owns 2 full-K gate rows, 16-step chunks,
//  pair-exchange, single d-bank, 1 barrier/step)
__global__ __launch_bounds__(256, 1) void k_scan(const float* __restrict__ xw,
                                                 const float* Whh,
                                                 float* hseq){
    __shared__ _Float16 hb[2][DIM];       // h ring (f16), uniform-read
    __shared__ float    stg[2][16][DIM];  // h staging for global flush
    const int tid = threadIdx.x;
    const int b = blockIdx.x;
    const int ci = tid >> 1;     // cell 0..127
    const int w  = tid & 1;      // gate-half: 0 -> {i,f}, 1 -> {g,o}

    WD32(pA) WD32(pB) WD32(pC) WD32(pD)   // gate 2w: A(K0-63)+B(K64-127); gate 2w+1: C+D
    {
        const float4* r0 = (const float4*)(Whh + (size_t)((2 * w    ) * DIM + ci) * DIM);
        const float4* r1 = (const float4*)(Whh + (size_t)((2 * w + 1) * DIM + ci) * DIM);
        WCVT32(pA, r0) WCVT32(pB, r0 + 16)
        WCVT32(pC, r1) WCVT32(pD, r1 + 16)
    }
    float cc = 0.f;
    if (tid < DIM) hb[0][tid] = (_Float16)0.f;
    const float2* xw2 = (const float2*)(xw + (size_t)b * SS * G4);   // [256][256] float2
    float* hout = hseq + (size_t)b * SS * DIM;
    __syncthreads();
    int p = 0;

#define SCAN_STEP(XC, CH, I) { \
        h2 d0,d1,d2,d3,d4,d5,d6,d7,d8,d9,d10,d11,d12,d13,d14,d15, \
           d16,d17,d18,d19,d20,d21,d22,d23,d24,d25,d26,d27,d28,d29,d30,d31; \
        float s0 = XC.x, s1 = XC.y; \
        RD32(&hb[p][0]) \
        DT32(pA, s0) DT32(pC, s1) \
        RD32(&hb[p][64]) \
        DT32(pB, s0) DT32(pD, s1) \
        float o0 = __shfl_xor(s0, 1), o1 = __shfl_xor(s1, 1); \
        float i_pre = w ? o0 : s0, f_pre = w ? o1 : s1; \
        float g_pre = w ? s0 : o0, o_pre = w ? s1 : o1; \
        float iv = sigm_(i_pre), fv = sigm_(f_pre); \
        float gv = tanh_(g_pre), ov = sigm_(o_pre); \
        cc = fv * cc + iv * gv; \
        float h = ov * tanh_(cc); \
        if (!w) hb[p ^ 1][ci] = (_Float16)h; \
        else    stg[(CH) & 1][I][ci] = h; \
        __syncthreads(); \
        p ^= 1; }

    for (int ch = 0; ch < 16; ++ch){
        if (ch > 0){   // flush previous chunk's 16x128 h tile (drains at next barrier)
#pragma unroll
            for (int j = 0; j < 2; ++j){
                int idx = j * 256 + tid;
                int r = idx >> 5, c4 = idx & 31;
                float4 v = *(const float4*)&stg[(ch - 1) & 1][r][c4 * 4];
                *(float4*)(hout + (size_t)((ch - 1) * 16 + r) * DIM + c4 * 4) = v;
            }
        }
        const int t0 = ch * 16;
        float2 xc0  = xw2[(t0 +  0) * 256 + tid], xc1  = xw2[(t0 +  1) * 256 + tid],
               xc2  = xw2[(t0 +  2) * 256 + tid], xc3  = xw2[(t0 +  3) * 256 + tid],
               xc4  = xw2[(t0 +  4) * 256 + tid], xc5  = xw2[(t0 +  5) * 256 + tid],
               xc6  = xw2[(t0 +  6) * 256 + tid], xc7  = xw2[(t0 +  7) * 256 + tid],
               xc8  = xw2[(t0 +  8) * 256 + tid], xc9  = xw2[(t0 +  9) * 256 + tid],
               xc10 = xw2[(t0 + 10) * 256 + tid], xc11 = xw2[(t0 + 11) * 256 + tid],
               xc12 = xw2[(t0 + 12) * 256 + tid], xc13 = xw2[(t0 + 13) * 256 + tid],
               xc14 = xw2[(t0 + 14) * 256 + tid], xc15 = xw2[(t0 + 15) * 256 + tid];
        SCAN_STEP(xc0,  ch, 0)  SCAN_STEP(xc1,  ch, 1)  SCAN_STEP(xc2,  ch, 2)  SCAN_STEP(xc3,  ch, 3)
        SCAN_STEP(xc4,  ch, 4)  SCAN_STEP(xc5,  ch, 5)  SCAN_STEP(xc6,  ch, 6)  SCAN_STEP(xc7,  ch, 7)
        SCAN_STEP(xc8,  ch, 8)  SCAN_STEP(xc9,  ch, 9)  SCAN_STEP(xc10, ch, 10) SCAN_STEP(xc11, ch, 11)
        SCAN_STEP(xc12, ch, 12) SCAN_STEP(xc13, ch, 13) SCAN_STEP(xc14, ch, 14) SCAN_STEP(xc15, ch, 15)
    }
    {   // final flush (chunk 15 -> stg buffer 1)
#pragma unroll
        for (int j = 0; j < 2; ++j){
            int idx = j * 256 + tid;
            int r = idx >> 5, c4 = idx & 31;
            float4 v = *(const float4*)&stg[1][r][c4 * 4];
            *(float4*)(hout + (size_t)(240 + r) * DIM + c4 * 4) = v;
        }
    }
#undef SCAN_STEP
}

// ---------------- K4: LayerNorm -> bf16 ----------------
__global__ void k_ln(const float* __restrict__ hseq, const float* __restrict__ gamma,
                     const float* __restrict__ beta, __hip_bfloat16* __restrict__ hn){
    int wid = threadIdx.x >> 6;
    int lane = threadIdx.x & 63;
    int row = blockIdx.x * 4 + wid;
    float2 hv = ((const float2*)(hseq + (size_t)row * DIM))[lane];
    float s = hv.x + hv.y;
    float sq = fmaf(hv.x, hv.x, hv.y * hv.y);
    for (int off = 32; off; off >>= 1){ s += __shfl_xor(s, off); sq += __shfl_xor(sq, off); }
    float mu = s * (1.f / 128.f);
    float var = sq * (1.f / 128.f) - mu * mu;
    float inv = rsqrtf(var + 1e-5f);
    float2 gv = ((const float2*)gamma)[lane];
    float2 bv = ((const float2*)beta)[lane];
    __hip_bfloat162 pr;
    pr.x = __float2bfloat16((hv.x - mu) * inv * gv.x + bv.x);
    pr.y = __float2bfloat16((hv.y - mu) * inv * gv.y + bv.y);
    ((__hip_bfloat162*)hn)[(size_t)row * 64 + lane] = pr;
}

// ---------------- K5: head_W fp32 -> bf16 ----------------
__global__ void k_cvt(const float* __restrict__ w, __hip_bfloat16* __restrict__ wb){
    int i = blockIdx.x * blockDim.x + threadIdx.x;
    float4 v = ((const float4*)w)[i];
    __hip_bfloat162 p0, p1;
    p0.x = __float2bfloat16(v.x); p0.y = __float2bfloat16(v.y);
    p1.x = __float2bfloat16(v.z); p1.y = __float2bfloat16(v.w);
    ((__hip_bfloat162*)wb)[2 * i]     = p0;
    ((__hip_bfloat162*)wb)[2 * i + 1] = p1;
}

// ---------------- K6: head GEMM — LDS epilogue + full-line NT stores ----------
// ROUND-15 CHANGE (isolated): stage the 128x128 fp32 tile in LDS [128][33]f32x4
// (67.6 KB, 2 blocks/CU), then 16 flat store passes: each 32-lane half-wave
// writes 512 B CONTIGUOUS (4 full 128-B lines) via nontemporal stores.
// Eliminates all 64-B partial-line NT writes (suspected ~2x HBM write RMW
// inflation; R13's instruction reorder couldn't prove it because WC merge
// across instructions is uncertain — staging removes the question).
// MFMA part + grid (250,64) x-major unchanged (R9-pinned).
__global__ __launch_bounds__(256) void k_head(const __hip_bfloat16* __restrict__ hn,
                                              const __hip_bfloat16* __restrict__ wb,
                                              const float* __restrict__ head_b,
                                              float* __restrict__ out){
    __shared__ f32x4 tile4[128 * 33];   // 67.6 KB
    int bn = blockIdx.x;
    int bm = blockIdx.y;
    int wid = threadIdx.x >> 6;
    int lane = threadIdx.x & 63;
    int wr = wid >> 1, wc = wid & 1;
    int row0 = bm * 128 + wr * 64;
    int col0 = bn * 128 + wc * 64;
    const short* A  = (const short*)hn;   // [8192][128]
    const short* Bp = (const short*)wb;   // [32000][128]
    f32x4 zero = {0.f, 0.f, 0.f, 0.f};
    f32x4 acc[4][4];
#pragma unroll
    for (int i = 0; i < 4; ++i)
#pragma unroll
        for (int j = 0; j < 4; ++j) acc[i][j] = zero;
    int lrow = lane & 15;
    int kgr = (lane >> 4) * 8;
#pragma unroll
    for (int ks = 0; ks < 4; ++ks){
        short8 a[4], bf[4];
#pragma unroll
        for (int mi = 0; mi < 4; ++mi)
            a[mi] = *(const short8*)(A + (size_t)(row0 + mi * 16 + lrow) * DIM + ks * 32 + kgr);
#pragma unroll
        for (int ni = 0; ni < 4; ++ni)
            bf[ni] = *(const short8*)(Bp + (size_t)(col0 + ni * 16 + lrow) * DIM + ks * 32 + kgr);
#pragma unroll
        for (int mi = 0; mi < 4; ++mi)
#pragma unroll
            for (int ni = 0; ni < 4; ++ni)
                acc[mi][ni] = __builtin_amdgcn_mfma_f32_16x16x32_bf16(bf[ni], a[mi], acc[mi][ni], 0, 0, 0);
    }
    int csub = (lane >> 4) * 4;
#pragma unroll
    for (int ni = 0; ni < 4; ++ni){
        int lc = wc * 64 + ni * 16 + csub;              // local col (mult of 4)
        float4 b4 = ((const float4*)head_b)[(bn * 128 + lc) >> 2];
#pragma unroll
        for (int mi = 0; mi < 4; ++mi){
            int lr = wr * 64 + mi * 16 + lrow;          // local row
            f32x4 v;
            v[0] = acc[mi][ni][0] + b4.x;
            v[1] = acc[mi][ni][1] + b4.y;
            v[2] = acc[mi][ni][2] + b4.z;
            v[3] = acc[mi][ni][3] + b4.w;
            tile4[lr * 33 + (lc >> 2)] = v;
        }
    }
    __syncthreads();
    const size_t gbase = (size_t)(bm * 128) * VOCAB + (size_t)bn * 128;
#pragma unroll
    for (int k = 0; k < 16; ++k){
        int f = k * 256 + threadIdx.x;     // flat float4 index 0..4095
        int r = f >> 5, c4 = f & 31;       // 32 lanes cover one row's 512 B contiguously
        f32x4 v = tile4[r * 33 + c4];
        __builtin_nontemporal_store(v, (f32x4*)(out + gbase + (size_t)r * VOCAB + c4 * 4));
    }
}

extern "C" void kernel_launch(void* const* d_in, const int* in_sizes, int n_in,
                              void* d_out, int out_size, void* d_ws, size_t ws_size,
                              hipStream_t stream){
    const int*   x     = (const int*)  d_in[0];
    const float* emb   = (const float*)d_in[1];
    const float* Wih   = (const float*)d_in[2];
    const float* Whh   = (const float*)d_in[3];
    const float* bih   = (const float*)d_in[4];
    const float* bhh   = (const float*)d_in[5];
    const float* gamma = (const float*)d_in[6];
    const float* beta  = (const float*)d_in[7];
    const float* headW = (const float*)d_in[8];
    const float* headb = (const float*)d_in[9];
    float* out = (float*)d_out;

    char* ws = (char*)d_ws;
    float* xw   = (float*)ws;                                  // 16 MB [8192][512] (cell-major)
    float* hseq = (float*)(ws + (16u << 20));                  // 4 MB  [8192][128]
    __hip_bfloat16* hn = (__hip_bfloat16*)(ws + (20u << 20));  // 2 MB
    __hip_bfloat16* wb = (__hip_bfloat16*)(ws + (22u << 20));  // 8 MB

    const size_t WSZ = (size_t)G4 * DIM;

    k_embed<<<1024, 256, 0, stream>>>(x, emb, hseq);
    k_cvt  <<<4000, 256, 0, stream>>>(headW, wb);
    for (int l = 0; l < NL; ++l){
        k_xw  <<<256, 512, 0, stream>>>(hseq, Wih + (size_t)l * WSZ,
                                        bih + l * G4, bhh + l * G4, xw);
        k_scan<<<32, 256, 0, stream>>>(xw, Whh + (size_t)l * WSZ, hseq);
    }
    k_ln   <<<2048, 256, 0, stream>>>(hseq, gamma, beta, hn);
    k_head <<<dim3(250, 64), 256, 0, stream>>>(hn, wb, headb, out);
}